// Round 21
// baseline (515.500 us; speedup 1.0000x reference)
//
#include <hip/hip_runtime.h>

#define N_PTS 131072
#define TILE 64
#define THREADS 512
#define REGION 40960   // per-head perm region (counts ~32.8K, >40 sigma headroom)

typedef __bf16 bf16;
typedef __bf16 bf16x8 __attribute__((ext_vector_type(8)));
typedef float f32x4 __attribute__((ext_vector_type(4)));

// ---------------- workspace layout (bytes) ----------------
#define WS_PERM_OFF   256                        // int perm[4][REGION]
#define WS_WPACK_OFF  (256 + 4 * REGION * 4)     // bf16 packed weights
// packed-weight element offsets (bf16 elements, all [out][K] "transposed")
#define OFF_W0     0          // [256][64]   (k=63 zero pad)
#define OFF_WS     16384      // [3][256][256]
#define OFF_TW0    212992     // [4][256][320] (k: 0..62 pts, 63 zero, 64..319 h)
#define OFF_TWS    540672     // [12][256][256]
#define OFF_FEATW  1327104    // [4][256][256]
#define OFF_VIEWSW 1589248    // [4][128][288] (k: 0..255 feat, 256..282 views, 283..287 zero)
#define TOTAL_PACK 1736704

// ---------------- LDS layout (bytes) ----------------
// H [64][256]bf16 32KB | PTS [64][64]bf16 8KB | VIEWS [64][32]bf16 4KB |
// pidx 256B. No B region (B: global->registers). 45KB -> 2 blocks/CU fit
// easily; occupancy is register-limited at 4 waves/SIMD.
#define H_BASE     0
#define PTS_BASE   32768
#define VIEWS_BASE 40960
#define PIDX_BASE  45056
#define LDS_BYTES  45312

__device__ __forceinline__ unsigned swz(unsigned base, unsigned row, unsigned rowstride,
                                        unsigned kbyte) {
  return (base + row * rowstride + kbyte) ^ ((row & 7u) << 4);
}

// ================= weight pack (k-major: coalesced reads) + head scatter ==========
__global__ void k_pack(const float* __restrict__ W0, const float* __restrict__ Ws,
                       const float* __restrict__ tW0, const float* __restrict__ tWs,
                       const float* __restrict__ featW, const float* __restrict__ viewsW,
                       bf16* __restrict__ out, const int* __restrict__ head,
                       int* __restrict__ ctrl, int* __restrict__ perm) {
  int gid = blockIdx.x * blockDim.x + threadIdx.x;
  if (gid < N_PTS) {
    int h = head[gid];
    int lane = threadIdx.x & 63;
    #pragma unroll
    for (int hh = 0; hh < 4; ++hh) {
      unsigned long long m = __ballot(h == hh);
      if (m == 0ull) continue;
      int leader = __builtin_ctzll(m);
      int base = 0;
      if (lane == leader) base = atomicAdd(&ctrl[16 + hh], __popcll(m));
      base = __shfl(base, leader);
      if (h == hh) {
        int rank = __popcll(m & ((1ull << lane) - 1ull));
        perm[hh * REGION + base + rank] = gid;
      }
    }
  }

  for (int idx = gid; idx < TOTAL_PACK; idx += gridDim.x * blockDim.x) {
    float v; int dst;
    if (idx < 16384) {                                   // W0: 64k x 256o
      int k = idx >> 8, o = idx & 255;
      v = (k < 63) ? W0[k * 256 + o] : 0.f;
      dst = OFF_W0 + o * 64 + k;
    } else if (idx < 212992) {                           // Ws: 3 x 256k x 256o
      int i = idx - 16384; int l = i >> 16, r = i & 65535, k = r >> 8, o = r & 255;
      v = Ws[i];
      dst = OFF_WS + l * 65536 + o * 256 + k;
    } else if (idx < 540672) {                           // tW0: 4 x 320k x 256o
      int i = idx - 212992; int h = i / 81920, r = i % 81920, k = r >> 8, o = r & 255;
      v = (k < 63) ? tW0[(h * 319 + k) * 256 + o]
                   : (k == 63 ? 0.f : tW0[(h * 319 + k - 1) * 256 + o]);
      dst = OFF_TW0 + h * 81920 + o * 320 + k;
    } else if (idx < 1327104) {                          // tWs: 12 x 256k x 256o
      int i = idx - 540672; int hj = i >> 16, r = i & 65535, k = r >> 8, o = r & 255;
      v = tWs[i];
      dst = OFF_TWS + hj * 65536 + o * 256 + k;
    } else if (idx < 1589248) {                          // featW: 4 x 256k x 256o
      int i = idx - 1327104; int h = i >> 16, r = i & 65535, k = r >> 8, o = r & 255;
      v = featW[i];
      dst = OFF_FEATW + h * 65536 + o * 256 + k;
    } else {                                             // viewsW: 4 x 288k x 128o
      int i = idx - 1589248; int h = i / 36864, r = i % 36864, k = r >> 7, o = r & 127;
      v = (k < 283) ? viewsW[(h * 283 + k) * 128 + o] : 0.f;
      dst = OFF_VIEWSW + h * 36864 + o * 288 + k;
    }
    out[dst] = (bf16)v;
  }
}

// ============ fused MLP layer: 8 waves x (64r x 32c), reg-B, barrier-free k-loop ===
// NF=2: acc = 8 f32x4 (32 regs) + bc/bn (16) + misc ~50 => ~100 unified regs
// => hardware co-schedules 2 blocks/CU = 16 waves/CU = 4 waves/SIMD --
// the first config combining 4/SIMD occupancy + no spill + no in-loop
// barriers (B private in regs; H read-only within a layer).
#define DOSTEP(KCV, BUF)                                                        \
  do {                                                                          \
    bf16x8 a[4];                                                                \
    if (PTS_FIRST ? ((KCV) < PKC) : ((KCV) >= LKC)) {                           \
      const int kcp = PTS_FIRST ? (KCV) : 0;                                    \
      _Pragma("unroll")                                                         \
      for (int m = 0; m < 4; ++m) {                                             \
        unsigned ad = (unsigned)(AUXB + (m * 16 + l15) * AUXSTR + kcp * 64 +    \
                                 l4 * 16) ^ axor;                               \
        a[m] = *(const bf16x8*)(lds + ad);                                      \
      }                                                                         \
    } else {                                                                    \
      unsigned va = acur ^ axor;                                                \
      _Pragma("unroll")                                                         \
      for (int m = 0; m < 4; ++m) a[m] = *(const bf16x8*)(lds + va + m * 8192); \
      acur += 64;                                                               \
    }                                                                           \
    __builtin_amdgcn_s_setprio(1);                                              \
    _Pragma("unroll")                                                           \
    for (int n = 0; n < NF; ++n)                                                \
      _Pragma("unroll")                                                         \
      for (int m = 0; m < 4; ++m)                                               \
        acc[m][n] = __builtin_amdgcn_mfma_f32_16x16x32_bf16(a[m], BUF[n],       \
                                                            acc[m][n], 0, 0, 0);\
    __builtin_amdgcn_s_setprio(0);                                              \
    if ((KCV) + 2 < KC) {                                                       \
      _Pragma("unroll")                                                         \
      for (int n = 0; n < NF; ++n)                                              \
        BUF[n] = *(const bf16x8*)(Wt + boff[n] + ((KCV) + 2) * 32);             \
    }                                                                           \
  } while (0)

template <int NF, bool RELU, int PKC, int LKC, bool PTS_FIRST, int AUXB, int AUXSTR>
__device__ __forceinline__ void mfma_layer(char* lds, const bf16* __restrict__ Wt,
                                           int wK, const float* __restrict__ bias,
                                           int lane, int wave) {
  const int l15 = lane & 15, l4 = lane >> 4;
  constexpr int KC = PKC + LKC;
  f32x4 acc[4][NF];
  #pragma unroll
  for (int m = 0; m < 4; ++m)
    #pragma unroll
    for (int n = 0; n < NF; ++n) acc[m][n] = (f32x4){0.f, 0.f, 0.f, 0.f};

  const int c0 = wave * (NF * 16);

  float bv[NF];
  #pragma unroll
  for (int n = 0; n < NF; ++n) bv[n] = bias[c0 + n * 16 + l15];

  // B global offsets (element units): frag(col, k) is 16B contiguous at
  // col*wK + kc*32 + l4*8 -- loaded straight into MFMA operand regs.
  int boff[NF];
  #pragma unroll
  for (int n = 0; n < NF; ++n) boff[n] = (c0 + n * 16 + l15) * wK + l4 * 8;

  // prologue: bc = chunk0, bn = chunk1
  bf16x8 bc[NF], bn[NF];
  #pragma unroll
  for (int n = 0; n < NF; ++n) bc[n] = *(const bf16x8*)(Wt + boff[n]);
  if (KC > 1) {
    #pragma unroll
    for (int n = 0; n < NF; ++n) bn[n] = *(const bf16x8*)(Wt + boff[n] + 32);
  }

  // A (H) cursor; XOR swizzle; m via 8192-byte immediates
  unsigned acur = (unsigned)(l15 * 512 + l4 * 16);
  const unsigned axor = (l15 & 7u) << 4;

  #pragma unroll 1
  for (int kc = 0; kc + 1 < KC; kc += 2) {
    DOSTEP(kc, bc);
    DOSTEP(kc + 1, bn);
  }
  if (KC & 1) DOSTEP(KC - 1, bc);

  // all waves' H reads retired (each wave's ds_reads complete before its
  // MFMAs, which precede its barrier arrival) -> in-place overwrite safe
  __builtin_amdgcn_s_barrier();

  #pragma unroll
  for (int n = 0; n < NF; ++n) {
    int col = c0 + n * 16 + l15;
    #pragma unroll
    for (int m = 0; m < 4; ++m) {
      #pragma unroll
      for (int j = 0; j < 4; ++j) {
        float v = acc[m][n][j] + bv[n];
        if (RELU) v = fmaxf(v, 0.f);
        int row = m * 16 + l4 * 4 + j;
        *(bf16*)(lds + swz(H_BASE, row, 512, col * 2)) = (bf16)v;
      }
    }
  }
  // fence: drains LDS writes; memory clobber keeps next layer's B loads
  // from hoisting above the barrier en masse
  asm volatile("s_waitcnt lgkmcnt(0)" ::: "memory");
  __builtin_amdgcn_s_barrier();
}

// ================= main fused kernel =================
// (512,3): 170-reg allocator budget (not squeezed; even a 84/86 carve fits
// arch ~66 + acc 32). Hardware occupancy from actual usage ~100 regs ->
// 2 blocks/CU = 4 waves/SIMD.
__global__ __launch_bounds__(THREADS, 3) void k_main(
    const float* __restrict__ x, const int* __restrict__ ctrl, const int* __restrict__ perm,
    const bf16* __restrict__ wpack,
    const float* __restrict__ b0, const float* __restrict__ bs,
    const float* __restrict__ tb0, const float* __restrict__ tbs,
    const float* __restrict__ featb, const float* __restrict__ alphaW,
    const float* __restrict__ alphab, const float* __restrict__ viewsb,
    const float* __restrict__ rgbW, const float* __restrict__ rgbb,
    float* __restrict__ outp) {
  __shared__ __attribute__((aligned(16))) char lds[LDS_BYTES];
  int* pidxl = (int*)(lds + PIDX_BASE);

  const int tid = threadIdx.x;
  const int lane = tid & 63, wave = tid >> 6;
  const int l15 = lane & 15, l4 = lane >> 4;

  // ---- fixed-grid head/tile mapping ----
  const int hh = blockIdx.x / (REGION / TILE);
  const int start = (blockIdx.x % (REGION / TILE)) * TILE;
  const int cnt = ctrl[16 + hh];
  if (start >= cnt) return;            // empty tile (uniform exit)
  const int nv = min(TILE, cnt - start);
  const int permbase = hh * REGION + start;

  if (tid < TILE) pidxl[tid] = (tid < nv) ? perm[permbase + tid] : 0;
  __syncthreads();

  // ---- gather pts [64][64] and views [64][32] into LDS (bf16, swizzled) ----
  for (int i = tid; i < TILE * 64; i += THREADS) {
    int row = i >> 6, c = i & 63;
    float v = (row < nv && c < 63) ? x[pidxl[row] * 90 + c] : 0.f;
    *(bf16*)(lds + ((PTS_BASE + row * 128 + c * 2) ^ ((row & 7u) << 4))) = (bf16)v;
  }
  for (int i = tid; i < TILE * 32; i += THREADS) {
    int row = i >> 5, c = i & 31;
    float v = (row < nv && c < 27) ? x[pidxl[row] * 90 + 63 + c] : 0.f;
    *(bf16*)(lds + ((VIEWS_BASE + row * 64 + c * 2) ^ ((row & 7u) << 4))) = (bf16)v;
  }
  __syncthreads();

  const bf16* W0p    = wpack + OFF_W0;
  const bf16* Wsp    = wpack + OFF_WS;
  const bf16* tW0p   = wpack + OFF_TW0 + hh * 81920;
  const bf16* tWsp   = wpack + OFF_TWS + hh * 3 * 65536;
  const bf16* featWp = wpack + OFF_FEATW + hh * 65536;
  const bf16* viewsWp= wpack + OFF_VIEWSW + hh * 36864;

  // trunk: W0 (A from PTS), 3x 256->256 (A from H)
  mfma_layer<2, true, 2, 0, true,  PTS_BASE, 128>(lds, W0p, 64, b0, lane, wave);
  mfma_layer<2, true, 0, 8, false, 0, 0>(lds, Wsp,          256, bs,       lane, wave);
  mfma_layer<2, true, 0, 8, false, 0, 0>(lds, Wsp + 65536,  256, bs + 256, lane, wave);
  mfma_layer<2, true, 0, 8, false, 0, 0>(lds, Wsp + 131072, 256, bs + 512, lane, wave);
  // T0: concat(pts[PTS], h[H]) 320 -> 256
  mfma_layer<2, true, 2, 8, true,  PTS_BASE, 128>(lds, tW0p, 320, tb0 + hh * 256, lane, wave);

  // head layers
  mfma_layer<2, true, 0, 8, false, 0, 0>(lds, tWsp,          256, tbs + hh * 768,       lane, wave);
  mfma_layer<2, true, 0, 8, false, 0, 0>(lds, tWsp + 65536,  256, tbs + hh * 768 + 256, lane, wave);
  mfma_layer<2, true, 0, 8, false, 0, 0>(lds, tWsp + 131072, 256, tbs + hh * 768 + 512, lane, wave);

  // ---- alpha = ha . alphaW[hh] + alphab (waves 0-3, rows wave*16+l15;
  //      reads complete before feat's pre-epilogue barrier) ----
  float my_alpha = 0.f;
  if (wave < 4) {
    int p = wave * 16 + l15;
    int kq = lane >> 4;
    const float* aW = alphaW + hh * 256;
    float s = 0.f;
    for (int i = 0; i < 8; ++i) {
      int k = kq * 64 + i * 8;
      bf16x8 hv8 = *(const bf16x8*)(lds + swz(H_BASE, p, 512, k * 2));
      #pragma unroll
      for (int j = 0; j < 8; ++j) s += (float)hv8[j] * aW[k + j];
    }
    s += __shfl_xor(s, 16);
    s += __shfl_xor(s, 32);
    my_alpha = s + alphab[hh];
  }

  // feat: 256->256 in-place, NO relu
  mfma_layer<2, false, 0, 8, false, 0, 0>(lds, featWp, 256, featb + hh * 256, lane, wave);
  // views: concat(feat[H], views[VIEWS]) 288 -> 128, relu, into H cols 0..127
  mfma_layer<1, true, 1, 8, false, VIEWS_BASE, 64>(lds, viewsWp, 288, viewsb + hh * 128,
                                                   lane, wave);

  // ---- rgb = hv . rgbW[hh] + rgbb ; write float4 {r,g,b,alpha} (waves 0-3) ----
  if (wave < 4) {
    int p = wave * 16 + l15;
    int kq = lane >> 4;
    const float* rW = rgbW + hh * 128 * 3;
    float r0 = 0.f, r1 = 0.f, r2 = 0.f;
    for (int i = 0; i < 4; ++i) {
      int k = kq * 32 + i * 8;
      bf16x8 hv8 = *(const bf16x8*)(lds + swz(H_BASE, p, 512, k * 2));
      #pragma unroll
      for (int j = 0; j < 8; ++j) {
        float hvf = (float)hv8[j];
        r0 += hvf * rW[(k + j) * 3 + 0];
        r1 += hvf * rW[(k + j) * 3 + 1];
        r2 += hvf * rW[(k + j) * 3 + 2];
      }
    }
    r0 += __shfl_xor(r0, 16); r0 += __shfl_xor(r0, 32);
    r1 += __shfl_xor(r1, 16); r1 += __shfl_xor(r1, 32);
    r2 += __shfl_xor(r2, 16); r2 += __shfl_xor(r2, 32);
    if (kq == 0 && p < nv) {
      int pt = pidxl[p];
      float4 o = make_float4(r0 + rgbb[hh * 3 + 0], r1 + rgbb[hh * 3 + 1],
                             r2 + rgbb[hh * 3 + 2], my_alpha);
      *(float4*)(outp + pt * 4) = o;
    }
  }
}

// ================= launch =================
extern "C" void kernel_launch(void* const* d_in, const int* in_sizes, int n_in,
                              void* d_out, int out_size, void* d_ws, size_t ws_size,
                              hipStream_t stream) {
  const float* x      = (const float*)d_in[0];
  const int*   head   = (const int*)d_in[1];
  const float* W0     = (const float*)d_in[2];
  const float* b0     = (const float*)d_in[3];
  const float* Ws     = (const float*)d_in[4];
  const float* bs     = (const float*)d_in[5];
  const float* tW0    = (const float*)d_in[6];
  const float* tb0    = (const float*)d_in[7];
  const float* tWs    = (const float*)d_in[8];
  const float* tbs    = (const float*)d_in[9];
  const float* featW  = (const float*)d_in[10];
  const float* featb  = (const float*)d_in[11];
  const float* alphaW = (const float*)d_in[12];
  const float* alphab = (const float*)d_in[13];
  const float* viewsW = (const float*)d_in[14];
  const float* viewsb = (const float*)d_in[15];
  const float* rgbW   = (const float*)d_in[16];
  const float* rgbb   = (const float*)d_in[17];

  int*  ctrl  = (int*)d_ws;
  int*  perm  = (int*)((char*)d_ws + WS_PERM_OFF);
  bf16* wpack = (bf16*)((char*)d_ws + WS_WPACK_OFF);

  hipMemsetAsync(ctrl, 0, 256, stream);
  k_pack<<<2048, 256, 0, stream>>>(W0, Ws, tW0, tWs, featW, viewsW, wpack, head, ctrl, perm);
  k_main<<<4 * (REGION / TILE), THREADS, 0, stream>>>(x, ctrl, perm, wpack,
                                                      b0, bs, tb0, tbs, featb, alphaW, alphab,
                                                      viewsb, rgbW, rgbb, (float*)d_out);
}

// Round 22
// 480.860 us; speedup vs baseline: 1.0720x; 1.0720x over previous
//
#include <hip/hip_runtime.h>

#define N_PTS 131072
#define TILE 64
#define THREADS 512
#define REGION 40960   // per-head perm region (counts ~32.8K, >40 sigma headroom)

typedef __bf16 bf16;
typedef __bf16 bf16x8 __attribute__((ext_vector_type(8)));
typedef float f32x4 __attribute__((ext_vector_type(4)));

// ---------------- workspace layout (bytes) ----------------
#define WS_PERM_OFF   256                        // int perm[4][REGION]
#define WS_WPACK_OFF  (256 + 4 * REGION * 4)     // bf16 packed weights
// packed-weight element offsets (bf16 elements, all [out][K] "transposed")
#define OFF_W0     0          // [256][64]   (k=63 zero pad)
#define OFF_WS     16384      // [3][256][256]
#define OFF_TW0    212992     // [4][256][320] (k: 0..62 pts, 63 zero, 64..319 h)
#define OFF_TWS    540672     // [12][256][256]
#define OFF_FEATW  1327104    // [4][256][256]
#define OFF_VIEWSW 1589248    // [4][128][288] (k: 0..255 feat, 256..282 views, 283..287 zero)
#define TOTAL_PACK 1736704

// ---------------- LDS layout (bytes) ----------------
// H [64][256]bf16 32KB | PTS [64][64]bf16 8KB | VIEWS [64][32]bf16 4KB |
// pidx 256B. No B region (B: global->registers). 45KB -> 2 blocks/CU fit.
#define H_BASE     0
#define PTS_BASE   32768
#define VIEWS_BASE 40960
#define PIDX_BASE  45056
#define LDS_BYTES  45312

__device__ __forceinline__ unsigned swz(unsigned base, unsigned row, unsigned rowstride,
                                        unsigned kbyte) {
  return (base + row * rowstride + kbyte) ^ ((row & 7u) << 4);
}

// ================= weight pack (k-major: coalesced reads) + head scatter ==========
__global__ void k_pack(const float* __restrict__ W0, const float* __restrict__ Ws,
                       const float* __restrict__ tW0, const float* __restrict__ tWs,
                       const float* __restrict__ featW, const float* __restrict__ viewsW,
                       bf16* __restrict__ out, const int* __restrict__ head,
                       int* __restrict__ ctrl, int* __restrict__ perm) {
  int gid = blockIdx.x * blockDim.x + threadIdx.x;
  if (gid < N_PTS) {
    int h = head[gid];
    int lane = threadIdx.x & 63;
    #pragma unroll
    for (int hh = 0; hh < 4; ++hh) {
      unsigned long long m = __ballot(h == hh);
      if (m == 0ull) continue;
      int leader = __builtin_ctzll(m);
      int base = 0;
      if (lane == leader) base = atomicAdd(&ctrl[16 + hh], __popcll(m));
      base = __shfl(base, leader);
      if (h == hh) {
        int rank = __popcll(m & ((1ull << lane) - 1ull));
        perm[hh * REGION + base + rank] = gid;
      }
    }
  }

  for (int idx = gid; idx < TOTAL_PACK; idx += gridDim.x * blockDim.x) {
    float v; int dst;
    if (idx < 16384) {                                   // W0: 64k x 256o
      int k = idx >> 8, o = idx & 255;
      v = (k < 63) ? W0[k * 256 + o] : 0.f;
      dst = OFF_W0 + o * 64 + k;
    } else if (idx < 212992) {                           // Ws: 3 x 256k x 256o
      int i = idx - 16384; int l = i >> 16, r = i & 65535, k = r >> 8, o = r & 255;
      v = Ws[i];
      dst = OFF_WS + l * 65536 + o * 256 + k;
    } else if (idx < 540672) {                           // tW0: 4 x 320k x 256o
      int i = idx - 212992; int h = i / 81920, r = i % 81920, k = r >> 8, o = r & 255;
      v = (k < 63) ? tW0[(h * 319 + k) * 256 + o]
                   : (k == 63 ? 0.f : tW0[(h * 319 + k - 1) * 256 + o]);
      dst = OFF_TW0 + h * 81920 + o * 320 + k;
    } else if (idx < 1327104) {                          // tWs: 12 x 256k x 256o
      int i = idx - 540672; int hj = i >> 16, r = i & 65535, k = r >> 8, o = r & 255;
      v = tWs[i];
      dst = OFF_TWS + hj * 65536 + o * 256 + k;
    } else if (idx < 1589248) {                          // featW: 4 x 256k x 256o
      int i = idx - 1327104; int h = i >> 16, r = i & 65535, k = r >> 8, o = r & 255;
      v = featW[i];
      dst = OFF_FEATW + h * 65536 + o * 256 + k;
    } else {                                             // viewsW: 4 x 288k x 128o
      int i = idx - 1589248; int h = i / 36864, r = i % 36864, k = r >> 7, o = r & 127;
      v = (k < 283) ? viewsW[(h * 283 + k) * 128 + o] : 0.f;
      dst = OFF_VIEWSW + h * 36864 + o * 288 + k;
    }
    out[dst] = (bf16)v;
  }
}

// ============ fused MLP layer: 8 waves x (64r x 32c), reg-B, barrier-free k-loop ===
// NF=2: acc = 8 f32x4 = 32 AGPR-slots; arch demand measured 84 (r21).
// At (512,4) the 128-reg unified budget carves 96 arch + 32 acc -> both
// fit -> 4 waves/SIMD AND spill-free simultaneously (the one cell of the
// {bound} x {acc-size} matrix not yet tried; all (512,4)+acc64 builds
// carved 64/64 and spilled, all smaller bounds ran 2 waves/SIMD).
#define DOSTEP(KCV, BUF)                                                        \
  do {                                                                          \
    bf16x8 a[4];                                                                \
    if (PTS_FIRST ? ((KCV) < PKC) : ((KCV) >= LKC)) {                           \
      const int kcp = PTS_FIRST ? (KCV) : 0;                                    \
      _Pragma("unroll")                                                         \
      for (int m = 0; m < 4; ++m) {                                             \
        unsigned ad = (unsigned)(AUXB + (m * 16 + l15) * AUXSTR + kcp * 64 +    \
                                 l4 * 16) ^ axor;                               \
        a[m] = *(const bf16x8*)(lds + ad);                                      \
      }                                                                         \
    } else {                                                                    \
      unsigned va = acur ^ axor;                                                \
      _Pragma("unroll")                                                         \
      for (int m = 0; m < 4; ++m) a[m] = *(const bf16x8*)(lds + va + m * 8192); \
      acur += 64;                                                               \
    }                                                                           \
    __builtin_amdgcn_s_setprio(1);                                              \
    _Pragma("unroll")                                                           \
    for (int n = 0; n < NF; ++n)                                                \
      _Pragma("unroll")                                                         \
      for (int m = 0; m < 4; ++m)                                               \
        acc[m][n] = __builtin_amdgcn_mfma_f32_16x16x32_bf16(a[m], BUF[n],       \
                                                            acc[m][n], 0, 0, 0);\
    __builtin_amdgcn_s_setprio(0);                                              \
    if ((KCV) + 2 < KC) {                                                       \
      _Pragma("unroll")                                                         \
      for (int n = 0; n < NF; ++n)                                              \
        BUF[n] = *(const bf16x8*)(Wt + boff[n] + ((KCV) + 2) * 32);             \
    }                                                                           \
  } while (0)

template <int NF, bool RELU, int PKC, int LKC, bool PTS_FIRST, int AUXB, int AUXSTR>
__device__ __forceinline__ void mfma_layer(char* lds, const bf16* __restrict__ Wt,
                                           int wK, const float* __restrict__ bias,
                                           int lane, int wave) {
  const int l15 = lane & 15, l4 = lane >> 4;
  constexpr int KC = PKC + LKC;
  f32x4 acc[4][NF];
  #pragma unroll
  for (int m = 0; m < 4; ++m)
    #pragma unroll
    for (int n = 0; n < NF; ++n) acc[m][n] = (f32x4){0.f, 0.f, 0.f, 0.f};

  const int c0 = wave * (NF * 16);

  float bv[NF];
  #pragma unroll
  for (int n = 0; n < NF; ++n) bv[n] = bias[c0 + n * 16 + l15];

  // B global offsets (element units): frag(col, k) is 16B contiguous at
  // col*wK + kc*32 + l4*8 -- loaded straight into MFMA operand regs.
  int boff[NF];
  #pragma unroll
  for (int n = 0; n < NF; ++n) boff[n] = (c0 + n * 16 + l15) * wK + l4 * 8;

  // prologue: bc = chunk0, bn = chunk1
  bf16x8 bc[NF], bn[NF];
  #pragma unroll
  for (int n = 0; n < NF; ++n) bc[n] = *(const bf16x8*)(Wt + boff[n]);
  if (KC > 1) {
    #pragma unroll
    for (int n = 0; n < NF; ++n) bn[n] = *(const bf16x8*)(Wt + boff[n] + 32);
  }

  // A (H) cursor; XOR swizzle; m via 8192-byte immediates
  unsigned acur = (unsigned)(l15 * 512 + l4 * 16);
  const unsigned axor = (l15 & 7u) << 4;

  #pragma unroll 1
  for (int kc = 0; kc + 1 < KC; kc += 2) {
    DOSTEP(kc, bc);
    DOSTEP(kc + 1, bn);
  }
  if (KC & 1) DOSTEP(KC - 1, bc);

  // all waves' H reads retired (each wave's ds_reads complete before its
  // MFMAs, which precede its barrier arrival) -> in-place overwrite safe
  __builtin_amdgcn_s_barrier();

  #pragma unroll
  for (int n = 0; n < NF; ++n) {
    int col = c0 + n * 16 + l15;
    #pragma unroll
    for (int m = 0; m < 4; ++m) {
      #pragma unroll
      for (int j = 0; j < 4; ++j) {
        float v = acc[m][n][j] + bv[n];
        if (RELU) v = fmaxf(v, 0.f);
        int row = m * 16 + l4 * 4 + j;
        *(bf16*)(lds + swz(H_BASE, row, 512, col * 2)) = (bf16)v;
      }
    }
  }
  // fence: drains LDS writes; memory clobber keeps next layer's B loads
  // from hoisting above the barrier en masse
  asm volatile("s_waitcnt lgkmcnt(0)" ::: "memory");
  __builtin_amdgcn_s_barrier();
}

// ================= main fused kernel =================
// (512,4): the occupancy that every fast round (r13/r15/r16, 318-340us)
// ran at. With acc=32 the 128-reg carve (96 arch + 32 acc) covers the
// measured 84-reg arch demand -> first spill-free 4-waves/SIMD build.
__global__ __launch_bounds__(THREADS, 4) void k_main(
    const float* __restrict__ x, const int* __restrict__ ctrl, const int* __restrict__ perm,
    const bf16* __restrict__ wpack,
    const float* __restrict__ b0, const float* __restrict__ bs,
    const float* __restrict__ tb0, const float* __restrict__ tbs,
    const float* __restrict__ featb, const float* __restrict__ alphaW,
    const float* __restrict__ alphab, const float* __restrict__ viewsb,
    const float* __restrict__ rgbW, const float* __restrict__ rgbb,
    float* __restrict__ outp) {
  __shared__ __attribute__((aligned(16))) char lds[LDS_BYTES];
  int* pidxl = (int*)(lds + PIDX_BASE);

  const int tid = threadIdx.x;
  const int lane = tid & 63, wave = tid >> 6;
  const int l15 = lane & 15, l4 = lane >> 4;

  // ---- fixed-grid head/tile mapping ----
  const int hh = blockIdx.x / (REGION / TILE);
  const int start = (blockIdx.x % (REGION / TILE)) * TILE;
  const int cnt = ctrl[16 + hh];
  if (start >= cnt) return;            // empty tile (uniform exit)
  const int nv = min(TILE, cnt - start);
  const int permbase = hh * REGION + start;

  if (tid < TILE) pidxl[tid] = (tid < nv) ? perm[permbase + tid] : 0;
  __syncthreads();

  // ---- gather pts [64][64] and views [64][32] into LDS (bf16, swizzled) ----
  for (int i = tid; i < TILE * 64; i += THREADS) {
    int row = i >> 6, c = i & 63;
    float v = (row < nv && c < 63) ? x[pidxl[row] * 90 + c] : 0.f;
    *(bf16*)(lds + ((PTS_BASE + row * 128 + c * 2) ^ ((row & 7u) << 4))) = (bf16)v;
  }
  for (int i = tid; i < TILE * 32; i += THREADS) {
    int row = i >> 5, c = i & 31;
    float v = (row < nv && c < 27) ? x[pidxl[row] * 90 + 63 + c] : 0.f;
    *(bf16*)(lds + ((VIEWS_BASE + row * 64 + c * 2) ^ ((row & 7u) << 4))) = (bf16)v;
  }
  __syncthreads();

  const bf16* W0p    = wpack + OFF_W0;
  const bf16* Wsp    = wpack + OFF_WS;
  const bf16* tW0p   = wpack + OFF_TW0 + hh * 81920;
  const bf16* tWsp   = wpack + OFF_TWS + hh * 3 * 65536;
  const bf16* featWp = wpack + OFF_FEATW + hh * 65536;
  const bf16* viewsWp= wpack + OFF_VIEWSW + hh * 36864;

  // trunk: W0 (A from PTS), 3x 256->256 (A from H)
  mfma_layer<2, true, 2, 0, true,  PTS_BASE, 128>(lds, W0p, 64, b0, lane, wave);
  mfma_layer<2, true, 0, 8, false, 0, 0>(lds, Wsp,          256, bs,       lane, wave);
  mfma_layer<2, true, 0, 8, false, 0, 0>(lds, Wsp + 65536,  256, bs + 256, lane, wave);
  mfma_layer<2, true, 0, 8, false, 0, 0>(lds, Wsp + 131072, 256, bs + 512, lane, wave);
  // T0: concat(pts[PTS], h[H]) 320 -> 256
  mfma_layer<2, true, 2, 8, true,  PTS_BASE, 128>(lds, tW0p, 320, tb0 + hh * 256, lane, wave);

  // head layers
  mfma_layer<2, true, 0, 8, false, 0, 0>(lds, tWsp,          256, tbs + hh * 768,       lane, wave);
  mfma_layer<2, true, 0, 8, false, 0, 0>(lds, tWsp + 65536,  256, tbs + hh * 768 + 256, lane, wave);
  mfma_layer<2, true, 0, 8, false, 0, 0>(lds, tWsp + 131072, 256, tbs + hh * 768 + 512, lane, wave);

  // ---- alpha = ha . alphaW[hh] + alphab (waves 0-3, rows wave*16+l15;
  //      reads complete before feat's pre-epilogue barrier) ----
  float my_alpha = 0.f;
  if (wave < 4) {
    int p = wave * 16 + l15;
    int kq = lane >> 4;
    const float* aW = alphaW + hh * 256;
    float s = 0.f;
    for (int i = 0; i < 8; ++i) {
      int k = kq * 64 + i * 8;
      bf16x8 hv8 = *(const bf16x8*)(lds + swz(H_BASE, p, 512, k * 2));
      #pragma unroll
      for (int j = 0; j < 8; ++j) s += (float)hv8[j] * aW[k + j];
    }
    s += __shfl_xor(s, 16);
    s += __shfl_xor(s, 32);
    my_alpha = s + alphab[hh];
  }

  // feat: 256->256 in-place, NO relu
  mfma_layer<2, false, 0, 8, false, 0, 0>(lds, featWp, 256, featb + hh * 256, lane, wave);
  // views: concat(feat[H], views[VIEWS]) 288 -> 128, relu, into H cols 0..127
  mfma_layer<1, true, 1, 8, false, VIEWS_BASE, 64>(lds, viewsWp, 288, viewsb + hh * 128,
                                                   lane, wave);

  // ---- rgb = hv . rgbW[hh] + rgbb ; write float4 {r,g,b,alpha} (waves 0-3) ----
  if (wave < 4) {
    int p = wave * 16 + l15;
    int kq = lane >> 4;
    const float* rW = rgbW + hh * 128 * 3;
    float r0 = 0.f, r1 = 0.f, r2 = 0.f;
    for (int i = 0; i < 4; ++i) {
      int k = kq * 32 + i * 8;
      bf16x8 hv8 = *(const bf16x8*)(lds + swz(H_BASE, p, 512, k * 2));
      #pragma unroll
      for (int j = 0; j < 8; ++j) {
        float hvf = (float)hv8[j];
        r0 += hvf * rW[(k + j) * 3 + 0];
        r1 += hvf * rW[(k + j) * 3 + 1];
        r2 += hvf * rW[(k + j) * 3 + 2];
      }
    }
    r0 += __shfl_xor(r0, 16); r0 += __shfl_xor(r0, 32);
    r1 += __shfl_xor(r1, 16); r1 += __shfl_xor(r1, 32);
    r2 += __shfl_xor(r2, 16); r2 += __shfl_xor(r2, 32);
    if (kq == 0 && p < nv) {
      int pt = pidxl[p];
      float4 o = make_float4(r0 + rgbb[hh * 3 + 0], r1 + rgbb[hh * 3 + 1],
                             r2 + rgbb[hh * 3 + 2], my_alpha);
      *(float4*)(outp + pt * 4) = o;
    }
  }
}

// ================= launch =================
extern "C" void kernel_launch(void* const* d_in, const int* in_sizes, int n_in,
                              void* d_out, int out_size, void* d_ws, size_t ws_size,
                              hipStream_t stream) {
  const float* x      = (const float*)d_in[0];
  const int*   head   = (const int*)d_in[1];
  const float* W0     = (const float*)d_in[2];
  const float* b0     = (const float*)d_in[3];
  const float* Ws     = (const float*)d_in[4];
  const float* bs     = (const float*)d_in[5];
  const float* tW0    = (const float*)d_in[6];
  const float* tb0    = (const float*)d_in[7];
  const float* tWs    = (const float*)d_in[8];
  const float* tbs    = (const float*)d_in[9];
  const float* featW  = (const float*)d_in[10];
  const float* featb  = (const float*)d_in[11];
  const float* alphaW = (const float*)d_in[12];
  const float* alphab = (const float*)d_in[13];
  const float* viewsW = (const float*)d_in[14];
  const float* viewsb = (const float*)d_in[15];
  const float* rgbW   = (const float*)d_in[16];
  const float* rgbb   = (const float*)d_in[17];

  int*  ctrl  = (int*)d_ws;
  int*  perm  = (int*)((char*)d_ws + WS_PERM_OFF);
  bf16* wpack = (bf16*)((char*)d_ws + WS_WPACK_OFF);

  hipMemsetAsync(ctrl, 0, 256, stream);
  k_pack<<<2048, 256, 0, stream>>>(W0, Ws, tW0, tWs, featW, viewsW, wpack, head, ctrl, perm);
  k_main<<<4 * (REGION / TILE), THREADS, 0, stream>>>(x, ctrl, perm, wpack,
                                                      b0, bs, tb0, tbs, featb, alphaW, alphab,
                                                      viewsb, rgbW, rgbb, (float*)d_out);
}